// Round 1
// baseline (359.861 us; speedup 1.0000x reference)
//
#include <hip/hip_runtime.h>

typedef _Float16 f16;
typedef _Float16 f16x8 __attribute__((ext_vector_type(8)));
typedef float f32x4 __attribute__((ext_vector_type(4)));

static constexpr size_t PART_STRIDE = (size_t)8192 * 256;

// ---------------- workspace layout (bytes) ----------------
static constexpr size_t OFF_W2   = 0;                                   // 16512*256 f16
static constexpr size_t SZ_W2    = (size_t)16512 * 256 * 2;
static constexpr size_t OFF_W3   = OFF_W2 + SZ_W2;                      // 16640*256 f16
static constexpr size_t SZ_W3    = (size_t)16640 * 256 * 2;
static constexpr size_t OFF_OT1  = OFF_W3 + SZ_W3;                      // 8192*128 f16 (swizzled)
static constexpr size_t OFF_XF2  = OFF_OT1 + (size_t)8192 * 128 * 2;    // 8192*128 f16 (swizzled)
static constexpr size_t OFF_C2   = OFF_XF2 + (size_t)8192 * 128 * 2;    // 256 f32
static constexpr size_t OFF_C3   = OFF_C2 + 1024;                       // 256 f32
static constexpr size_t OFF_ACC  = OFF_C3 + 1024;                       // 8192 f32
static constexpr size_t OFF_PART = OFF_ACC + 32768;                     // 4*8192*256 f32

// ---------------- weight pre-swizzle into fragment-linear f16 ----------------
// Wswz[((s*16 + nt)*64 + l)*8 + e] = Weff[k = 32 s + (l>>4)*8 + e][n = nt*16 + (l&15)]
template<int LAYER>
__global__ __launch_bounds__(256)
void prep_w(const float* __restrict__ Wf, const float* __restrict__ Wg,
            f16* __restrict__ Wswz)
{
    const int t = blockIdx.x * 256 + threadIdx.x;
    const int s = t >> 10, rem = t & 1023;
    const int nt = rem >> 6, l = rem & 63;
    const int n = nt * 16 + (l & 15);
    const int kb = s * 32 + (l >> 4) * 8;
    f16x8 o;
#pragma unroll
    for (int e = 0; e < 8; ++e) {
        const int k = kb + e;
        int row;
        if (LAYER == 2) row = (k < 128) ? (1 + k) : (129 + (k - 128));
        else            row = (k < 128) ? (1 + k)
                              : ((k < 256) ? (129 + (k - 128)) : (257 + (k - 256)));
        const float v = (n < 128) ? Wf[(size_t)row * 128 + n]
                                  : Wg[(size_t)row * 128 + (n - 128)];
        o[e] = (f16)v;
    }
    *(f16x8*)(Wswz + (size_t)t * 8) = o;
}

// ---------------- bias-row constants: c[n] = b[n] + bias0 * W[0,n] ----------------
__global__ __launch_bounds__(256)
void prep_small(const float* __restrict__ bias0,
                const float* __restrict__ Wf2, const float* __restrict__ bf2,
                const float* __restrict__ Wg2, const float* __restrict__ bg2,
                const float* __restrict__ Wf3, const float* __restrict__ bf3,
                const float* __restrict__ Wg3, const float* __restrict__ bg3,
                float* __restrict__ c2, float* __restrict__ c3)
{
    const int n = threadIdx.x;
    const float b0 = bias0[0];
    if (n < 128) { c2[n] = bf2[n] + b0 * Wf2[n]; c3[n] = bf3[n] + b0 * Wf3[n]; }
    else { const int m = n - 128; c2[n] = bg2[m] + b0 * Wg2[m]; c3[n] = bg3[m] + b0 * Wg3[m]; }
}

// ---------------- layer 1: ot1/og1 + their final-dot contribution ----------------
__global__ __launch_bounds__(256)
void layer1_poly(const float* __restrict__ x, const float* __restrict__ bias0,
                 const float* __restrict__ Wf1, const float* __restrict__ bf1,
                 const float* __restrict__ Wg1, const float* __restrict__ bg1,
                 const float* __restrict__ Wfc, const float* __restrict__ bfc,
                 f16* __restrict__ ot1f16, float* __restrict__ outacc)
{
    const int half = threadIdx.x >> 7;   // 2 rows per block
    const int n = threadIdx.x & 127;
    const int r = blockIdx.x * 2 + half;
    const float b0 = bias0[0];
    float sf = b0 * Wf1[n] + bf1[n];
    float sg = b0 * Wg1[n] + bg1[n];
    const float* xr = x + (size_t)r * 64;
#pragma unroll 8
    for (int k = 0; k < 64; ++k) {
        const float xv = xr[k];
        sf = fmaf(xv, Wf1[(k + 1) * 128 + n], sf);
        sg = fmaf(xv, Wg1[(k + 1) * 128 + n], sg);
    }
    // swizzled f16 store (feature layout for the GEMM kernels)
    ot1f16[(size_t)r * 128 + (n ^ ((r & 7) << 3))] = (f16)sf;
    float p = sf * Wfc[1 + n] + sg * Wfc[385 + n];
#pragma unroll
    for (int off = 32; off; off >>= 1) p += __shfl_down(p, off);
    __shared__ float wp[4];
    if ((threadIdx.x & 63) == 0) wp[threadIdx.x >> 6] = p;
    __syncthreads();
    if ((threadIdx.x & 127) == 0)
        outacc[r] = bfc[0] + b0 * Wfc[0] + wp[half * 2] + wp[half * 2 + 1];
}

// ---------------- main GEMM: on-the-fly outer-product A, K-split ----------------
// LAYER==2: K = 128 (ot1 linear) + 16384 (ot1 x ot1)       = 516 k-steps of 32
// LAYER==3: K = 128 (ot1) + 128 (xf2) + 16384 (ot1 x xf2)  = 520 k-steps of 32
template<int LAYER>
__global__ __launch_bounds__(512)
void gemm_poly(const f16* __restrict__ Wswz, const f16* __restrict__ featg,
               const f16* __restrict__ ot1g, float* __restrict__ partials)
{
    extern __shared__ char smem[];
    f16* feat = (f16*)smem;              // 128 rows x 128 f16 (swizzled), 32 KB
    f16* wbuf = (f16*)(smem + 32768);    // 2 x 8192 f16 (one 32-k step each), 32 KB

    const int bid = blockIdx.x;
    const int rb = bid >> 2, sp = bid & 3;
    const int r0 = rb * 128;
    const int tid = threadIdx.x;

    // stage feature tile (ot1 for L2, xf2 for L3) - already swizzled in global
    for (int u = tid; u < 2048; u += 512)
        *(f16x8*)(feat + (size_t)u * 8) = *(const f16x8*)(featg + (size_t)r0 * 128 + (size_t)u * 8);

    const int NLIN = (LAYER == 2) ? 4 : 8;     // linear-region k-steps
    const int s_start = sp * 128 + (sp ? NLIN : 0);
    const int s_end = sp * 128 + 128 + NLIN;
    const int nst = s_end - s_start;

    const int wid = tid >> 6, lane = tid & 63;
    const int wr = wid >> 2, wc = wid & 3;     // 2 x 4 wave grid
    const int lhi = lane >> 4, llo = lane & 15;

    f32x4 acc[4][4] = {};

    {   // prologue: stage first W k-step
        const f16* src = Wswz + (size_t)s_start * 8192;
        *(f16x8*)(wbuf + tid * 16)     = *(const f16x8*)(src + tid * 16);
        *(f16x8*)(wbuf + tid * 16 + 8) = *(const f16x8*)(src + tid * 16 + 8);
    }
    __syncthreads();

    f16 o1h[4];
    int icur = -1;

    for (int c = 0; c < nst; ++c) {
        const int s = s_start + c;
        const bool more = (c + 1 < nst);
        f16x8 w0, w1;
        if (more) {   // issue next-step loads early (hide under compute)
            const f16* src = Wswz + (size_t)(s + 1) * 8192;
            w0 = *(const f16x8*)(src + tid * 16);
            w1 = *(const f16x8*)(src + tid * 16 + 8);
        }

        // ---- A fragments (4 M-tiles) ----
        f16x8 afr[4];
        if (s < NLIN) {     // linear region: A = feature slice directly
#pragma unroll
            for (int mi = 0; mi < 4; ++mi) {
                const int rl = wr * 64 + mi * 16 + llo;
                if (LAYER == 2) {
                    const int j0 = 32 * s + lhi * 8;
                    afr[mi] = *(const f16x8*)(feat + rl * 128 + (j0 ^ ((rl & 7) << 3)));
                } else if (s < 4) {   // ot1 slice from global (L2-resident, 4 steps only)
                    const int j0 = 32 * s + lhi * 8;
                    const int rg = r0 + rl;
                    afr[mi] = *(const f16x8*)(ot1g + (size_t)rg * 128 + (j0 ^ ((rg & 7) << 3)));
                } else {              // xf2 slice from LDS
                    const int j0 = 32 * (s - 4) + lhi * 8;
                    afr[mi] = *(const f16x8*)(feat + rl * 128 + (j0 ^ ((rl & 7) << 3)));
                }
            }
        } else {            // outer-product region: A = o1[r,i] * feat[r, j0..j0+7]
            const int ku = (s - NLIN) * 32;
            const int i = ku >> 7;
            const int j0 = (ku & 127) + lhi * 8;
            if (i != icur) {      // o1 scalar changes every 4 k-steps (uniform branch)
                icur = i;
#pragma unroll
                for (int mi = 0; mi < 4; ++mi) {
                    const int rl = wr * 64 + mi * 16 + llo;
                    if (LAYER == 2)
                        o1h[mi] = feat[rl * 128 + (i ^ ((rl & 7) << 3))];
                    else {
                        const int rg = r0 + rl;
                        o1h[mi] = ot1g[(size_t)rg * 128 + (i ^ ((rg & 7) << 3))];
                    }
                }
            }
#pragma unroll
            for (int mi = 0; mi < 4; ++mi) {
                const int rl = wr * 64 + mi * 16 + llo;
                const f16x8 sl = *(const f16x8*)(feat + rl * 128 + (j0 ^ ((rl & 7) << 3)));
                afr[mi] = sl * o1h[mi];
            }
        }

        // ---- B fragments + MFMA ----
        const f16* wb = wbuf + (c & 1) * 8192;
#pragma unroll
        for (int ni = 0; ni < 4; ++ni) {
            const int nt = wc * 4 + ni;
            const f16x8 bfr = *(const f16x8*)(wb + (nt * 64 + lane) * 8);
#pragma unroll
            for (int mi = 0; mi < 4; ++mi)
                acc[mi][ni] = __builtin_amdgcn_mfma_f32_16x16x32_f16(afr[mi], bfr, acc[mi][ni], 0, 0, 0);
        }

        if (more) {   // write next W step into the other buffer
            f16* dst = wbuf + ((c + 1) & 1) * 8192;
            *(f16x8*)(dst + tid * 16)     = w0;
            *(f16x8*)(dst + tid * 16 + 8) = w1;
        }
        __syncthreads();
    }

    // ---- epilogue: partial C (f32) ----
    float* pout = partials + (size_t)sp * PART_STRIDE + (size_t)r0 * 256;
#pragma unroll
    for (int mi = 0; mi < 4; ++mi) {
#pragma unroll
        for (int ni = 0; ni < 4; ++ni) {
            const int col = wc * 64 + ni * 16 + llo;
            const int rbase = wr * 64 + mi * 16 + lhi * 4;
#pragma unroll
            for (int q = 0; q < 4; ++q)
                pout[(size_t)(rbase + q) * 256 + col] = acc[mi][ni][q];
        }
    }
}

// ---------------- K-split reduction + bias const + final-dot contribution ----------------
template<int LAYER>
__global__ __launch_bounds__(256)
void reduce_poly(const float* __restrict__ partials, const float* __restrict__ cvec,
                 const float* __restrict__ Wfc, f16* __restrict__ xf_out,
                 float* __restrict__ outacc, float* __restrict__ outp)
{
    const int r = blockIdx.x;
    const int n = threadIdx.x;
    const size_t idx = (size_t)r * 256 + n;
    float v = partials[idx] + partials[idx + PART_STRIDE]
            + partials[idx + 2 * PART_STRIDE] + partials[idx + 3 * PART_STRIDE];
    v += cvec[n];
    if (LAYER == 2 && n < 128)
        xf_out[(size_t)r * 128 + (n ^ ((r & 7) << 3))] = (f16)v;
    const int wseg = (LAYER == 2) ? (n < 128 ? 129 + n : 513 + (n - 128))
                                  : (n < 128 ? 257 + n : 641 + (n - 128));
    float p = v * Wfc[wseg];
#pragma unroll
    for (int off = 32; off; off >>= 1) p += __shfl_down(p, off);
    __shared__ float wp[4];
    if ((threadIdx.x & 63) == 0) wp[threadIdx.x >> 6] = p;
    __syncthreads();
    if (threadIdx.x == 0) {
        const float tot = wp[0] + wp[1] + wp[2] + wp[3];
        if (LAYER == 2) outacc[r] += tot;
        else            outp[r] = outacc[r] + tot;
    }
}

// ---------------- host launcher ----------------
extern "C" void kernel_launch(void* const* d_in, const int* in_sizes, int n_in,
                              void* d_out, int out_size, void* d_ws, size_t ws_size,
                              hipStream_t stream)
{
    (void)in_sizes; (void)n_in; (void)out_size; (void)ws_size;
    const float* x     = (const float*)d_in[0];
    const float* bias0 = (const float*)d_in[1];
    const float* Wf1   = (const float*)d_in[2];
    const float* bf1   = (const float*)d_in[3];
    const float* Wg1   = (const float*)d_in[4];
    const float* bg1   = (const float*)d_in[5];
    const float* Wf2   = (const float*)d_in[6];
    const float* bf2   = (const float*)d_in[7];
    const float* Wg2   = (const float*)d_in[8];
    const float* bg2   = (const float*)d_in[9];
    const float* Wf3   = (const float*)d_in[10];
    const float* bf3   = (const float*)d_in[11];
    const float* Wg3   = (const float*)d_in[12];
    const float* bg3   = (const float*)d_in[13];
    const float* Wfc   = (const float*)d_in[14];
    const float* bfc   = (const float*)d_in[15];
    float* out = (float*)d_out;

    char* ws = (char*)d_ws;
    f16*   W2s    = (f16*)(ws + OFF_W2);
    f16*   W3s    = (f16*)(ws + OFF_W3);
    f16*   ot1f16 = (f16*)(ws + OFF_OT1);
    f16*   xf2f16 = (f16*)(ws + OFF_XF2);
    float* c2     = (float*)(ws + OFF_C2);
    float* c3     = (float*)(ws + OFF_C3);
    float* outacc = (float*)(ws + OFF_ACC);
    float* parts  = (float*)(ws + OFF_PART);

    prep_w<2><<<2064, 256, 0, stream>>>(Wf2, Wg2, W2s);   // 516*1024/256
    prep_w<3><<<2080, 256, 0, stream>>>(Wf3, Wg3, W3s);   // 520*1024/256
    prep_small<<<1, 256, 0, stream>>>(bias0, Wf2, bf2, Wg2, bg2, Wf3, bf3, Wg3, bg3, c2, c3);
    layer1_poly<<<4096, 256, 0, stream>>>(x, bias0, Wf1, bf1, Wg1, bg1, Wfc, bfc, ot1f16, outacc);
    gemm_poly<2><<<256, 512, 65536, stream>>>(W2s, ot1f16, ot1f16, parts);
    reduce_poly<2><<<8192, 256, 0, stream>>>(parts, c2, Wfc, xf2f16, outacc, out);
    gemm_poly<3><<<256, 512, 65536, stream>>>(W3s, xf2f16, ot1f16, parts);
    reduce_poly<3><<<8192, 256, 0, stream>>>(parts, c3, Wfc, nullptr, outacc, out);
}

// Round 6
// 312.620 us; speedup vs baseline: 1.1511x; 1.1511x over previous
//
#include <hip/hip_runtime.h>

typedef _Float16 f16;
typedef _Float16 f16x8 __attribute__((ext_vector_type(8)));
typedef float f32x4 __attribute__((ext_vector_type(4)));

static constexpr size_t PART_STRIDE = (size_t)8192 * 256;

// ---------------- workspace layout (bytes) ----------------
static constexpr size_t OFF_W2   = 0;                                   // 516 steps * 8192 f16
static constexpr size_t SZ_W2    = (size_t)516 * 8192 * 2;
static constexpr size_t OFF_W3   = OFF_W2 + SZ_W2;                      // 520 steps * 8192 f16
static constexpr size_t SZ_W3    = (size_t)520 * 8192 * 2;
static constexpr size_t OFF_OT1  = OFF_W3 + SZ_W3;                      // 8192*128 f16 (row-major)
static constexpr size_t OFF_XF2  = OFF_OT1 + (size_t)8192 * 128 * 2;    // 8192*128 f16 (row-major)
static constexpr size_t OFF_C2   = OFF_XF2 + (size_t)8192 * 128 * 2;    // 256 f32
static constexpr size_t OFF_C3   = OFF_C2 + 1024;                       // 256 f32
static constexpr size_t OFF_ACC  = OFF_C3 + 1024;                       // 8192 f32
static constexpr size_t OFF_PART = OFF_ACC + 32768;                     // 4*8192*256 f32

// ---------------- weight pre-swizzle into fragment-linear f16 ----------------
// K enumeration (jw outer, i inner) so GEMM A-slices stay in registers:
//   step s, lane l, elem e: kl = (l>>4)*8+e
//   L2: s<4  -> row = 1 + s*32 + kl            (linear: ot1 cols)
//       else u=s-4:  row = 129 + (u&127)*128 + (u>>7)*32 + kl
//   L3: s<8  -> row = 1 + s*32 + kl            (linear: [ot1|xf2] cols)
//       else u=s-8:  row = 257 + (u&127)*128 + (u>>7)*32 + kl
// Wswz[((s*16 + nt)*64 + l)*8 + e] = Weff[row][n = nt*16 + (l&15)]
// => element stride: step = 8192 f16, 64-col quarter nb = contiguous 2048 f16.
template<int LAYER>
__global__ __launch_bounds__(256)
void prep_w(const float* __restrict__ Wf, const float* __restrict__ Wg,
            f16* __restrict__ Wswz)
{
    const int t = blockIdx.x * 256 + threadIdx.x;
    const int s = t >> 10, rem = t & 1023;
    const int nt = rem >> 6, l = rem & 63;
    const int n = nt * 16 + (l & 15);
    const int klb = (l >> 4) * 8;
    f16x8 o;
#pragma unroll
    for (int e = 0; e < 8; ++e) {
        const int kl = klb + e;
        int row;
        if (LAYER == 2) {
            if (s < 4) row = 1 + s * 32 + kl;
            else { const int u = s - 4; row = 129 + (u & 127) * 128 + (u >> 7) * 32 + kl; }
        } else {
            if (s < 8) row = 1 + s * 32 + kl;
            else { const int u = s - 8; row = 257 + (u & 127) * 128 + (u >> 7) * 32 + kl; }
        }
        const float v = (n < 128) ? Wf[(size_t)row * 128 + n]
                                  : Wg[(size_t)row * 128 + (n - 128)];
        o[e] = (f16)v;
    }
    *(f16x8*)(Wswz + (size_t)t * 8) = o;
}

// ---------------- bias-row constants: c[n] = b[n] + bias0 * W[0,n] ----------------
__global__ __launch_bounds__(256)
void prep_small(const float* __restrict__ bias0,
                const float* __restrict__ Wf2, const float* __restrict__ bf2,
                const float* __restrict__ Wg2, const float* __restrict__ bg2,
                const float* __restrict__ Wf3, const float* __restrict__ bf3,
                const float* __restrict__ Wg3, const float* __restrict__ bg3,
                float* __restrict__ c2, float* __restrict__ c3)
{
    const int n = threadIdx.x;
    const float b0 = bias0[0];
    if (n < 128) { c2[n] = bf2[n] + b0 * Wf2[n]; c3[n] = bf3[n] + b0 * Wf3[n]; }
    else { const int m = n - 128; c2[n] = bg2[m] + b0 * Wg2[m]; c3[n] = bg3[m] + b0 * Wg3[m]; }
}

// ---------------- layer 1: ot1/og1 + their final-dot contribution ----------------
__global__ __launch_bounds__(256)
void layer1_poly(const float* __restrict__ x, const float* __restrict__ bias0,
                 const float* __restrict__ Wf1, const float* __restrict__ bf1,
                 const float* __restrict__ Wg1, const float* __restrict__ bg1,
                 const float* __restrict__ Wfc, const float* __restrict__ bfc,
                 f16* __restrict__ ot1f16, float* __restrict__ outacc)
{
    const int half = threadIdx.x >> 7;   // 2 rows per block
    const int n = threadIdx.x & 127;
    const int r = blockIdx.x * 2 + half;
    const float b0 = bias0[0];
    float sf = b0 * Wf1[n] + bf1[n];
    float sg = b0 * Wg1[n] + bg1[n];
    const float* xr = x + (size_t)r * 64;
#pragma unroll 8
    for (int k = 0; k < 64; ++k) {
        const float xv = xr[k];
        sf = fmaf(xv, Wf1[(k + 1) * 128 + n], sf);
        sg = fmaf(xv, Wg1[(k + 1) * 128 + n], sg);
    }
    ot1f16[(size_t)r * 128 + n] = (f16)sf;     // row-major (unswizzled)
    float p = sf * Wfc[1 + n] + sg * Wfc[385 + n];
#pragma unroll
    for (int off = 32; off; off >>= 1) p += __shfl_down(p, off);
    __shared__ float wp[4];
    if ((threadIdx.x & 63) == 0) wp[threadIdx.x >> 6] = p;
    __syncthreads();
    if ((threadIdx.x & 127) == 0)
        outacc[r] = bfc[0] + b0 * Wfc[0] + wp[half * 2] + wp[half * 2 + 1];
}

// ---------------- main GEMM v2: register-resident A, global_load_lds B ----------------
// Block: 256M x 64N, 4 waves (2M x 2N), wave tile 128M x 32N (mi=8, ni=2).
// Grid: 32 rb x 4 sp x 4 nb = 512 blocks -> 2 blocks/CU, 8 waves/CU.
// Split sp: CLIN linear steps + 128 outer steps (jw = sp, i = 0..127).

#define STAGE(S_W, BUF) do {                                                        \
    const f16* _src = wsrc0 + (size_t)(S_W) * 8192;                                 \
    __builtin_amdgcn_global_load_lds(                                               \
        (const __attribute__((address_space(1))) unsigned int*)_src,                \
        (__attribute__((address_space(3))) unsigned int*)&wbuf[BUF][tid * 8],       \
        16, 0, 0);                                                                  \
} while (0)

#define GBODY(O1CUR, O1NXT, I8)                                                     \
{                                                                                   \
    _Pragma("unroll")                                                               \
    for (int e = 0; e < 8; ++e) {                                                   \
        const int cc = (I8) * 8 + e;                                                \
        if (e < 7) { STAGE(out_base + cc + 1, (CLIN + e + 1) & 1); }                \
        else if ((I8) < 15) { STAGE(out_base + cc + 1, (CLIN + e + 1) & 1); }       \
        if (e == 0) {                                                               \
            _Pragma("unroll")                                                       \
            for (int mi = 0; mi < 8; ++mi)                                          \
                O1NXT[mi] = *(const f16x8*)(ot1_row + mi * 2048 + ((I8) + 1) * 8);  \
        }                                                                           \
        f16x8 afr[8];                                                               \
        _Pragma("unroll")                                                           \
        for (int mi = 0; mi < 8; ++mi)                                              \
            afr[mi] = featreg[mi] * O1CUR[mi][e];                                   \
        const f16* wb = &wbuf[(CLIN + e) & 1][0];                                   \
        _Pragma("unroll")                                                           \
        for (int ni = 0; ni < 2; ++ni) {                                            \
            const f16x8 bfr = *(const f16x8*)(wb + ((wc * 2 + ni) * 64 + lane) * 8);\
            _Pragma("unroll")                                                       \
            for (int mi = 0; mi < 8; ++mi)                                          \
                acc[mi][ni] = __builtin_amdgcn_mfma_f32_16x16x32_f16(               \
                    afr[mi], bfr, acc[mi][ni], 0, 0, 0);                            \
        }                                                                           \
        __syncthreads();                                                            \
    }                                                                               \
}

template<int LAYER>
__global__ __launch_bounds__(256, 2)
void gemm_poly(const f16* __restrict__ Wswz, const f16* featg,
               const f16* ot1g, float* __restrict__ partials)
{
    __shared__ f16 wbuf[2][2048];            // 2 x 4KB B double-buffer

    constexpr int NLIN = (LAYER == 2) ? 4 : 8;   // global linear k-steps
    constexpr int CLIN = (LAYER == 2) ? 1 : 2;   // linear steps per split

    const int bid = blockIdx.x;
    const int rb = bid >> 4;                 // 0..31
    const int sp = (bid >> 2) & 3;           // k-split / jw
    const int nb = bid & 3;                  // N quarter (64 cols)
    const int r0 = rb * 256;
    const int tid = threadIdx.x;
    const int wid = tid >> 6, lane = tid & 63;
    const int wr = wid >> 1, wc = wid & 1;   // 2M x 2N wave grid
    const int lhi = lane >> 4, llo = lane & 15;

    const f16* wsrc0 = Wswz + nb * 2048 + tid * 8;   // 64-col quarter, element units
    const f16* ot1_row  = ot1g  + (size_t)(r0 + wr * 128 + llo) * 128;  // + mi*2048
    const f16* feat_row = featg + (size_t)(r0 + wr * 128 + llo) * 128;

    f32x4 acc[8][2] = {};
    const int out_base = NLIN + sp * 128;

    // prologue: stage first step, load register-resident A slices + first o1 block
    STAGE(CLIN * sp, 0);
    f16x8 featreg[8], o1A[8], o1B[8];
#pragma unroll
    for (int mi = 0; mi < 8; ++mi) {
        featreg[mi] = *(const f16x8*)(feat_row + mi * 2048 + sp * 32 + lhi * 8);
        o1A[mi]     = *(const f16x8*)(ot1_row + mi * 2048);
    }
    __syncthreads();

    // ---- linear steps ----
#pragma unroll
    for (int c = 0; c < CLIN; ++c) {
        const int s = CLIN * sp + c;
        STAGE((c + 1 < CLIN) ? (s + 1) : out_base, (c + 1) & 1);
        f16x8 afr[8];
        const int col = s * 32 + lhi * 8;
#pragma unroll
        for (int mi = 0; mi < 8; ++mi) {
            if (LAYER == 2) afr[mi] = *(const f16x8*)(ot1_row + mi * 2048 + col);
            else afr[mi] = (col < 128) ? *(const f16x8*)(ot1_row + mi * 2048 + col)
                                       : *(const f16x8*)(feat_row + mi * 2048 + (col - 128));
        }
        const f16* wb = &wbuf[c & 1][0];
#pragma unroll
        for (int ni = 0; ni < 2; ++ni) {
            const f16x8 bfr = *(const f16x8*)(wb + ((wc * 2 + ni) * 64 + lane) * 8);
#pragma unroll
            for (int mi = 0; mi < 8; ++mi)
                acc[mi][ni] = __builtin_amdgcn_mfma_f32_16x16x32_f16(afr[mi], bfr, acc[mi][ni], 0, 0, 0);
        }
        __syncthreads();
    }

    // ---- outer-product region: 128 steps (jw = sp fixed, i inner) ----
    for (int i8 = 0; i8 < 16; i8 += 2) {
        GBODY(o1A, o1B, i8);
        GBODY(o1B, o1A, i8 + 1);
    }

    // ---- epilogue: partial C (f32) ----
    float* pout = partials + (size_t)sp * PART_STRIDE
                + (size_t)(r0 + wr * 128) * 256 + nb * 64 + wc * 32 + llo;
#pragma unroll
    for (int mi = 0; mi < 8; ++mi)
#pragma unroll
        for (int ni = 0; ni < 2; ++ni)
#pragma unroll
            for (int q = 0; q < 4; ++q)
                pout[(size_t)(mi * 16 + lhi * 4 + q) * 256 + ni * 16] = acc[mi][ni][q];
}

#undef GBODY
#undef STAGE

// ---------------- K-split reduction + bias const + final-dot contribution ----------------
template<int LAYER>
__global__ __launch_bounds__(256)
void reduce_poly(const float* __restrict__ partials, const float* __restrict__ cvec,
                 const float* __restrict__ Wfc, f16* __restrict__ xf_out,
                 float* __restrict__ outacc, float* __restrict__ outp)
{
    const int r = blockIdx.x;
    const int n = threadIdx.x;
    const size_t idx = (size_t)r * 256 + n;
    float v = partials[idx] + partials[idx + PART_STRIDE]
            + partials[idx + 2 * PART_STRIDE] + partials[idx + 3 * PART_STRIDE];
    v += cvec[n];
    if (LAYER == 2 && n < 128)
        xf_out[(size_t)r * 128 + n] = (f16)v;       // row-major (unswizzled)
    const int wseg = (LAYER == 2) ? (n < 128 ? 129 + n : 513 + (n - 128))
                                  : (n < 128 ? 257 + n : 641 + (n - 128));
    float p = v * Wfc[wseg];
#pragma unroll
    for (int off = 32; off; off >>= 1) p += __shfl_down(p, off);
    __shared__ float wp[4];
    if ((threadIdx.x & 63) == 0) wp[threadIdx.x >> 6] = p;
    __syncthreads();
    if (threadIdx.x == 0) {
        const float tot = wp[0] + wp[1] + wp[2] + wp[3];
        if (LAYER == 2) outacc[r] += tot;
        else            outp[r] = outacc[r] + tot;
    }
}

// ---------------- host launcher ----------------
extern "C" void kernel_launch(void* const* d_in, const int* in_sizes, int n_in,
                              void* d_out, int out_size, void* d_ws, size_t ws_size,
                              hipStream_t stream)
{
    (void)in_sizes; (void)n_in; (void)out_size; (void)ws_size;
    const float* x     = (const float*)d_in[0];
    const float* bias0 = (const float*)d_in[1];
    const float* Wf1   = (const float*)d_in[2];
    const float* bf1   = (const float*)d_in[3];
    const float* Wg1   = (const float*)d_in[4];
    const float* bg1   = (const float*)d_in[5];
    const float* Wf2   = (const float*)d_in[6];
    const float* bf2   = (const float*)d_in[7];
    const float* Wg2   = (const float*)d_in[8];
    const float* bg2   = (const float*)d_in[9];
    const float* Wf3   = (const float*)d_in[10];
    const float* bf3   = (const float*)d_in[11];
    const float* Wg3   = (const float*)d_in[12];
    const float* bg3   = (const float*)d_in[13];
    const float* Wfc   = (const float*)d_in[14];
    const float* bfc   = (const float*)d_in[15];
    float* out = (float*)d_out;

    char* ws = (char*)d_ws;
    f16*   W2s    = (f16*)(ws + OFF_W2);
    f16*   W3s    = (f16*)(ws + OFF_W3);
    f16*   ot1f16 = (f16*)(ws + OFF_OT1);
    f16*   xf2f16 = (f16*)(ws + OFF_XF2);
    float* c2     = (float*)(ws + OFF_C2);
    float* c3     = (float*)(ws + OFF_C3);
    float* outacc = (float*)(ws + OFF_ACC);
    float* parts  = (float*)(ws + OFF_PART);

    prep_w<2><<<2064, 256, 0, stream>>>(Wf2, Wg2, W2s);   // 516*1024/256
    prep_w<3><<<2080, 256, 0, stream>>>(Wf3, Wg3, W3s);   // 520*1024/256
    prep_small<<<1, 256, 0, stream>>>(bias0, Wf2, bf2, Wg2, bg2, Wf3, bf3, Wg3, bg3, c2, c3);
    layer1_poly<<<4096, 256, 0, stream>>>(x, bias0, Wf1, bf1, Wg1, bg1, Wfc, bfc, ot1f16, outacc);
    gemm_poly<2><<<512, 256, 0, stream>>>(W2s, ot1f16, ot1f16, parts);
    reduce_poly<2><<<8192, 256, 0, stream>>>(parts, c2, Wfc, xf2f16, outacc, out);
    gemm_poly<3><<<512, 256, 0, stream>>>(W3s, xf2f16, ot1f16, parts);
    reduce_poly<3><<<8192, 256, 0, stream>>>(parts, c3, Wfc, nullptr, outacc, out);
}